// Round 2
// baseline (431.564 us; speedup 1.0000x reference)
//
#include <hip/hip_runtime.h>

// PolynomialLayer: in (N,3) f32 -> out (N,10) f32
// out row = [1, x0, x1, x2, x0^2, x0*x1, x0*x2, x1^2, x1*x2, x2^2]
//
// R2 strategy: store-coalesced decomposition. Assign each thread OUTPUT
// float4 indices g (lane-consecutive -> each store instruction writes
// 64 contiguous float4 = 1KB). Since lcm(4,10) = 20 floats = 5 float4
// = 2 rows, g%5 statically selects which 4 terms this lane emits and
// g/5 selects the input row-pair (6 floats = 3 aligned float2 loads,
// shared by 5 neighboring lanes -> merged by the coalescer).

__global__ __launch_bounds__(256) void poly_coal_kernel(const float2* __restrict__ in2,
                                                        float4* __restrict__ out4,
                                                        int nOut4) {
    int idx = blockIdx.x * blockDim.x + threadIdx.x;
    int stride = gridDim.x * blockDim.x;
    for (int g = idx; g < nOut4; g += stride) {
        unsigned ug = (unsigned)g;
        unsigned p = ug / 5u;        // row-pair index (rows 2p, 2p+1)
        unsigned rem = ug - p * 5u;  // 0..4: which float4 within the 20-float pair
        size_t pb = 3 * (size_t)p;
        float2 a = in2[pb + 0];
        float2 b = in2[pb + 1];
        float2 c = in2[pb + 2];
        float xa0 = a.x, xa1 = a.y, xa2 = b.x;   // row A = 2p
        float xb0 = b.y, xb1 = c.x, xb2 = c.y;   // row B = 2p+1
        // floats 20p+4*rem .. +3 of the output:
        // rem0: A cols 0-3 | rem1: A cols 4-7 | rem2: A cols 8-9 + B cols 0-1
        // rem3: B cols 2-5 | rem4: B cols 6-9
        float4 v0 = make_float4(1.0f, xa0, xa1, xa2);
        float4 v1 = make_float4(xa0 * xa0, xa0 * xa1, xa0 * xa2, xa1 * xa1);
        float4 v2 = make_float4(xa1 * xa2, xa2 * xa2, 1.0f, xb0);
        float4 v3 = make_float4(xb1, xb2, xb0 * xb0, xb0 * xb1);
        float4 v4 = make_float4(xb0 * xb2, xb1 * xb1, xb1 * xb2, xb2 * xb2);
        float4 v = (rem == 0) ? v0
                 : (rem == 1) ? v1
                 : (rem == 2) ? v2
                 : (rem == 3) ? v3
                              : v4;
        out4[g] = v;  // lane-consecutive: 64x16B contiguous per instruction
    }
}

// Scalar tail for an odd final row (not hit at N=8e6).
__global__ void poly_tail_kernel(const float* __restrict__ in,
                                 float* __restrict__ out,
                                 int startRow, int nRows) {
    int i = startRow + blockIdx.x * blockDim.x + threadIdx.x;
    if (i >= nRows) return;
    float x0 = in[3 * (long long)i + 0];
    float x1 = in[3 * (long long)i + 1];
    float x2 = in[3 * (long long)i + 2];
    float* p = &out[10 * (long long)i];
    p[0] = 1.0f; p[1] = x0; p[2] = x1; p[3] = x2;
    p[4] = x0 * x0; p[5] = x0 * x1; p[6] = x0 * x2;
    p[7] = x1 * x1; p[8] = x1 * x2; p[9] = x2 * x2;
}

extern "C" void kernel_launch(void* const* d_in, const int* in_sizes, int n_in,
                              void* d_out, int out_size, void* d_ws, size_t ws_size,
                              hipStream_t stream) {
    const float* in = (const float*)d_in[0];
    float* out = (float*)d_out;
    int nRows = in_sizes[0] / 3;
    int nPairs = nRows / 2;
    int nOut4 = nPairs * 5;  // float4s covering complete row-pairs

    if (nOut4 > 0) {
        int block = 256;
        int maxBlocks = 2048;  // 256 CUs x 8 blocks, grid-stride the rest
        int blocks = (nOut4 + block - 1) / block;
        if (blocks > maxBlocks) blocks = maxBlocks;
        poly_coal_kernel<<<blocks, block, 0, stream>>>((const float2*)in, (float4*)out, nOut4);
    }
    int done = nPairs * 2;
    if (done < nRows) {  // odd final row
        poly_tail_kernel<<<1, 64, 0, stream>>>(in, out, done, nRows);
    }
}

// Round 3
// 81.632 us; speedup vs baseline: 5.2867x; 5.2867x over previous
//
#include <hip/hip_runtime.h>

// PolynomialLayer: in (N,3) f32 -> out (N,10) f32
// out row = [1, x0, x1, x2, x0^2, x0*x1, x0*x2, x1^2, x1*x2, x2^2]
//
// R3: LDS-staged output for fill-identical stores.
//   - Each thread computes 4 rows (3x float4 loads, per-thread contiguous).
//   - Writes its 40 floats to a wave-private LDS row padded to 41 dwords
//     (stride 41 == 9 mod 32, coprime -> <=2-way bank conflicts, free).
//   - Wave then reads back output-linear and stores out4[base + q*64+lane]:
//     every store instruction = 64 consecutive float4 = 1KB full lines,
//     the same pattern the harness fill kernel runs at ~6.9 TB/s.
//   - LDS slices are wave-private -> no __syncthreads needed.

#define BLOCK 256
#define ROW_DW 41  // 40 output floats + 1 pad dword

__global__ __launch_bounds__(BLOCK) void poly_lds_kernel(const float4* __restrict__ in4,
                                                         float4* __restrict__ out4,
                                                         int nChunks) {
    __shared__ float lds[4][64 * ROW_DW];  // 4 waves x 10.496 KB = 41.98 KB
    const int lane = threadIdx.x & 63;
    const int wid = threadIdx.x >> 6;
    float* wlds = lds[wid];

    int idx = blockIdx.x * BLOCK + threadIdx.x;
    int stride = gridDim.x * BLOCK;
    for (int c = idx;; c += stride) {
        int waveBase = c - lane;  // wave-uniform
        if (waveBase >= nChunks) break;
        bool fullWave = (waveBase + 64 <= nChunks);
        bool valid = (c < nChunks);

        float o[40];
        if (valid) {
            float4 a = in4[3 * c + 0];
            float4 b = in4[3 * c + 1];
            float4 d = in4[3 * c + 2];
            float r[4][3] = {{a.x, a.y, a.z},
                             {a.w, b.x, b.y},
                             {b.z, b.w, d.x},
                             {d.y, d.z, d.w}};
#pragma unroll
            for (int i = 0; i < 4; ++i) {
                float x0 = r[i][0], x1 = r[i][1], x2 = r[i][2];
                o[i * 10 + 0] = 1.0f;
                o[i * 10 + 1] = x0;
                o[i * 10 + 2] = x1;
                o[i * 10 + 3] = x2;
                o[i * 10 + 4] = x0 * x0;
                o[i * 10 + 5] = x0 * x1;
                o[i * 10 + 6] = x0 * x2;
                o[i * 10 + 7] = x1 * x1;
                o[i * 10 + 8] = x1 * x2;
                o[i * 10 + 9] = x2 * x2;
            }
        }

        if (fullWave) {
            // stage 40 floats into padded wave-private LDS row
            float* myrow = &wlds[ROW_DW * lane];
#pragma unroll
            for (int k = 0; k < 40; ++k) myrow[k] = o[k];
            // read back output-linear, store fully coalesced
            float4* wout = out4 + 10ll * (long long)waveBase;
#pragma unroll
            for (int q = 0; q < 10; ++q) {
                unsigned j = (unsigned)(q * 64 + lane);   // 0..639
                unsigned m = j / 10u;                     // source lane
                unsigned r = j - 10u * m;                 // its r-th float4
                const float* s = &wlds[ROW_DW * m + 4u * r];
                wout[j] = make_float4(s[0], s[1], s[2], s[3]);
            }
        } else if (valid) {
            // rare ragged wave: direct per-thread stores (R1 pattern)
            float4* po = out4 + 10ll * (long long)c;
#pragma unroll
            for (int jj = 0; jj < 10; ++jj)
                po[jj] = make_float4(o[4 * jj + 0], o[4 * jj + 1], o[4 * jj + 2], o[4 * jj + 3]);
        }
    }
}

// Scalar tail for nRows % 4 != 0 (not hit at N=8e6).
__global__ void poly_tail_kernel(const float* __restrict__ in,
                                 float* __restrict__ out,
                                 int startRow, int nRows) {
    int i = startRow + blockIdx.x * blockDim.x + threadIdx.x;
    if (i >= nRows) return;
    float x0 = in[3 * (long long)i + 0];
    float x1 = in[3 * (long long)i + 1];
    float x2 = in[3 * (long long)i + 2];
    float* p = &out[10 * (long long)i];
    p[0] = 1.0f; p[1] = x0; p[2] = x1; p[3] = x2;
    p[4] = x0 * x0; p[5] = x0 * x1; p[6] = x0 * x2;
    p[7] = x1 * x1; p[8] = x1 * x2; p[9] = x2 * x2;
}

extern "C" void kernel_launch(void* const* d_in, const int* in_sizes, int n_in,
                              void* d_out, int out_size, void* d_ws, size_t ws_size,
                              hipStream_t stream) {
    const float* in = (const float*)d_in[0];
    float* out = (float*)d_out;
    int nRows = in_sizes[0] / 3;
    int nChunks = nRows / 4;

    if (nChunks > 0) {
        int blocks = (nChunks + BLOCK - 1) / BLOCK;
        if (blocks > 2048) blocks = 2048;
        poly_lds_kernel<<<blocks, BLOCK, 0, stream>>>((const float4*)in, (float4*)out, nChunks);
    }
    int done = nChunks * 4;
    if (done < nRows) {
        poly_tail_kernel<<<1, 64, 0, stream>>>(in, out, done, nRows);
    }
}